// Round 8
// baseline (206.598 us; speedup 1.0000x reference)
//
#include <hip/hip_runtime.h>
#include <hip/hip_bf16.h>

// Problem constants (B=2, S=2048, D=512, H=8, hd=64)
constexpr int Bc = 2, Sc = 2048, Dc = 512, Hc = 8, HDc = 64;
constexpr float NEGC = 10000.0f;
constexpr float SCALEC = 0.125f; // 1/sqrt(64)
constexpr int Mtot = Bc * Sc;    // 4096
constexpr size_t HEADMAT = (size_t)Bc * Hc * Sc * HDc;  // 2M elems

typedef __attribute__((ext_vector_type(8))) short          short8;
typedef __attribute__((ext_vector_type(4))) short          short4v;
typedef __attribute__((ext_vector_type(4))) float          f32x4;

static __device__ __forceinline__ unsigned short f32_to_bf16_bits(float f) {
    unsigned int u = __builtin_bit_cast(unsigned int, f);
    unsigned int r = u + 0x7FFFu + ((u >> 16) & 1u);   // RNE
    return (unsigned short)(r >> 16);
}

// ---------------------------------------------------------------------------
// x f32 -> bf16 (row-major [M][512] unchanged layout)
// ---------------------------------------------------------------------------
__global__ __launch_bounds__(256)
void convert_x(const float* __restrict__ x, unsigned short* __restrict__ Xb, int n)
{
    const int i = (blockIdx.x * 256 + threadIdx.x) * 4;
    if (i >= n) return;
    const float4 v = *(const float4*)(x + i);
    ushort4 o;
    o.x = f32_to_bf16_bits(v.x);
    o.y = f32_to_bf16_bits(v.y);
    o.z = f32_to_bf16_bits(v.z);
    o.w = f32_to_bf16_bits(v.w);
    *(ushort4*)(Xb + i) = o;
}

// ---------------------------------------------------------------------------
// W [512][512] f32 -> W^T [512][512] bf16, z = {Wq,Wk,Wv,Wo}. 64x64 LDS tile.
// ---------------------------------------------------------------------------
__global__ __launch_bounds__(256)
void transpose_w(const float* __restrict__ W0, const float* __restrict__ W1,
                 const float* __restrict__ W2, const float* __restrict__ W3,
                 unsigned short* __restrict__ Wt)
{
    __shared__ float T[64][65];
    const int z = blockIdx.z;
    const float* Wp = (z == 0) ? W0 : (z == 1) ? W1 : (z == 2) ? W2 : W3;
    unsigned short* Op = Wt + (size_t)z * 512 * 512;

    const int kt = blockIdx.y * 64, nt = blockIdx.x * 64;
    const int t = threadIdx.x;
    const int r  = t >> 2, c4 = (t & 3) * 16;

    #pragma unroll
    for (int i = 0; i < 4; ++i) {
        const float4 v = *(const float4*)(Wp + (size_t)(kt + r) * 512 + nt + c4 + 4 * i);
        T[r][c4 + 4*i + 0] = v.x;
        T[r][c4 + 4*i + 1] = v.y;
        T[r][c4 + 4*i + 2] = v.z;
        T[r][c4 + 4*i + 3] = v.w;
    }
    __syncthreads();

    const int n = t >> 2, k4 = (t & 3) * 16;
    #pragma unroll
    for (int i = 0; i < 4; ++i) {
        ushort4 o;
        o.x = f32_to_bf16_bits(T[k4 + 4*i + 0][n]);
        o.y = f32_to_bf16_bits(T[k4 + 4*i + 1][n]);
        o.z = f32_to_bf16_bits(T[k4 + 4*i + 2][n]);
        o.w = f32_to_bf16_bits(T[k4 + 4*i + 3][n]);
        *(ushort4*)(Op + (size_t)(nt + n) * 512 + kt + k4 + 4 * i) = o;
    }
}

// ---------------------------------------------------------------------------
// bf16 MFMA GEMM: Y[M,512] = relu(X[M,512] @ W + bias), W given as W^T bf16.
// HEADOUT: Q,K (z=0,1) -> bf16 head-major [z][B][H][S][64];
//          V (z=2)     -> bf16 head-TRANSPOSED [B][H][64][S].
// else: f32 row-major [M][512].
// ---------------------------------------------------------------------------
template<bool HEADOUT>
__global__ __launch_bounds__(256)
void gemm_mfma(const unsigned short* __restrict__ Xb,
               const unsigned short* __restrict__ Wt,
               const float* __restrict__ b0, const float* __restrict__ b1,
               const float* __restrict__ b2,
               unsigned short* __restrict__ Hout,
               float* __restrict__ Yf)
{
    const int lane = threadIdx.x & 63, wave = threadIdx.x >> 6;
    const int c = lane & 15, g = lane >> 4;
    const int z = blockIdx.z;
    const unsigned short* Wp = Wt + (size_t)z * 512 * 512;
    const float* bp = (z == 0) ? b0 : (z == 1) ? b1 : b2;
    const int m0 = blockIdx.y * 64 + wave * 16;
    const int n0 = blockIdx.x * 64;

    const unsigned short* arow = Xb + (size_t)(m0 + c) * 512 + g * 8;
    const unsigned short* brow = Wp + (size_t)(n0 + c) * 512 + g * 8;

    f32x4 acc[4] = {{0.f,0.f,0.f,0.f},{0.f,0.f,0.f,0.f},
                    {0.f,0.f,0.f,0.f},{0.f,0.f,0.f,0.f}};

    #pragma unroll
    for (int k0 = 0; k0 < 512; k0 += 32) {
        const short8 a = *(const short8*)(arow + k0);
        #pragma unroll
        for (int t = 0; t < 4; ++t) {
            const short8 b = *(const short8*)(brow + (size_t)t * 16 * 512 + k0);
            acc[t] = __builtin_amdgcn_mfma_f32_16x16x32_bf16(a, b, acc[t], 0, 0, 0);
        }
    }

    #pragma unroll
    for (int t = 0; t < 4; ++t) {
        const int n = n0 + 16 * t + c;
        const float bias = bp[n];
        float v[4];
        #pragma unroll
        for (int r = 0; r < 4; ++r) v[r] = fmaxf(acc[t][r] + bias, 0.0f);

        if constexpr (HEADOUT) {
            const int mbase = m0 + 4 * g;
            const int bb = mbase >> 11, ss = mbase & 2047;
            const int hh = n >> 6, hd = n & 63;
            if (z == 2) {
                // V transposed: Vt[(bb*H+hh)][hd][ss..ss+3], vectorized store
                union { ushort4 u; unsigned short s[4]; } pk;
                #pragma unroll
                for (int r = 0; r < 4; ++r) pk.s[r] = f32_to_bf16_bits(v[r]);
                *reinterpret_cast<ushort4*>(
                    Hout + (size_t)2 * HEADMAT +
                    ((size_t)(bb * Hc + hh) * HDc + hd) * Sc + ss) = pk.u;
            } else {
                #pragma unroll
                for (int r = 0; r < 4; ++r)
                    Hout[(size_t)z * HEADMAT +
                         (((size_t)(bb * Hc + hh) * Sc + ss + r) * HDc + hd)] =
                        f32_to_bf16_bits(v[r]);
            }
        } else {
            #pragma unroll
            for (int r = 0; r < 4; ++r)
                Yf[(size_t)(m0 + 4 * g + r) * 512 + n] = v[r];
        }
    }
}

// ---------------------------------------------------------------------------
// Split-K MFMA flash attention, v4.
// Block = 16 q-rows of one (b,h); 4 waves take INTERLEAVED 32-key chunks
// (wave w: k0 = w*32 + 128j) -> balanced makespan ~kend/128 per wave.
// - XCD swizzle: swz=(bid&7)*256+(bid>>3) -> 2 heads per XCD, K/V L2-resident.
// - V from transposed global layout Vt[b,h][64][S]: 8 x 8B vector loads per
//   iter, issued BEFORE softmax so L2 latency hides (no LDS in the loop).
// - Defer-rescale: skip corr/rescale/shfl block when __all(tmax <= m) --
//   bit-exact (corr would be expf(0)=1).
// - Combine in LDS as before; empty chunks carry weight exactly 0.0f.
// ---------------------------------------------------------------------------
__global__ __launch_bounds__(256)
void attn_mfma(const short* __restrict__ Qh, const short* __restrict__ Kh,
               const short* __restrict__ Vt, const int* __restrict__ mask,
               unsigned short* __restrict__ Ob)
{
    __shared__ float Lacc[4][16][65];
    __shared__ float Lm[4][16];
    __shared__ float Ll[4][16];

    const int lane = threadIdx.x & 63;
    const int wave = threadIdx.x >> 6;
    const int bid = blockIdx.x;
    const int swz = (bid & 7) * 256 + (bid >> 3);   // 2048 % 8 == 0: bijective
    const int qt  = swz & 127;
    const int h   = (swz >> 7) & 7;
    const int b   = swz >> 10;
    const int q0  = qt * 16;
    const int c   = lane & 15;
    const int g   = lane >> 4;

    const size_t headoff = (size_t)(b * Hc + h) * Sc * HDc;
    const short* Qp = Qh + headoff;
    const short* Kp = Kh + headoff;
    const short* Vp = Vt + headoff;          // [64][Sc] within head
    const int* mb = mask + b * Sc;

    // first unmasked key index (block-uniform)
    int fb = Sc;
    for (int base = 0; base < Sc; base += 64) {
        unsigned long long bal = __ballot(mb[base + lane] != 0);
        if (bal) { fb = base + (__ffsll((unsigned long long)bal) - 1); break; }
    }
    const int kmax = (fb <= q0) ? (q0 + 16) : Sc;
    const int kend = (kmax + 31) & ~31;

    const short8 qf0 = *(const short8*)(Qp + (size_t)(q0 + c) * HDc + g * 8);
    const short8 qf1 = *(const short8*)(Qp + (size_t)(q0 + c) * HDc + 32 + g * 8);

    f32x4 acc[4] = {{0.f,0.f,0.f,0.f},{0.f,0.f,0.f,0.f},
                    {0.f,0.f,0.f,0.f},{0.f,0.f,0.f,0.f}};
    float m = -1e30f, l = 0.0f;

    for (int k0 = wave * 32; k0 < kend; k0 += 128) {
        // --- K fragments
        const short8 kf0a = *(const short8*)(Kp + (size_t)(k0 + c) * HDc + g * 8);
        const short8 kf0b = *(const short8*)(Kp + (size_t)(k0 + c) * HDc + 32 + g * 8);
        const short8 kf1a = *(const short8*)(Kp + (size_t)(k0 + 16 + c) * HDc + g * 8);
        const short8 kf1b = *(const short8*)(Kp + (size_t)(k0 + 16 + c) * HDc + 32 + g * 8);

        // --- V fragments issued early (consumed only by PV at the bottom;
        //     L2 latency hides under QK^T + softmax)
        short4v va[4], vb[4];
        #pragma unroll
        for (int t = 0; t < 4; ++t) {
            const short* vrow = Vp + (size_t)(t * 16 + c) * Sc + k0 + 4 * g;
            va[t] = *(const short4v*)(vrow);
            vb[t] = *(const short4v*)(vrow + 16);
        }

        // --- QK^T
        f32x4 s0 = {0.f, 0.f, 0.f, 0.f};
        f32x4 s1 = {0.f, 0.f, 0.f, 0.f};
        s0 = __builtin_amdgcn_mfma_f32_16x16x32_bf16(kf0a, qf0, s0, 0, 0, 0);
        s0 = __builtin_amdgcn_mfma_f32_16x16x32_bf16(kf0b, qf1, s0, 0, 0, 0);
        s1 = __builtin_amdgcn_mfma_f32_16x16x32_bf16(kf1a, qf0, s1, 0, 0, 0);
        s1 = __builtin_amdgcn_mfma_f32_16x16x32_bf16(kf1b, qf1, s1, 0, 0, 0);

        const int4 mka = *(const int4*)(mb + k0 + 4 * g);
        const int4 mkb = *(const int4*)(mb + k0 + 16 + 4 * g);
        const int mia[4] = {mka.x, mka.y, mka.z, mka.w};
        const int mib[4] = {mkb.x, mkb.y, mkb.z, mkb.w};

        // --- masked scores + per-row max
        float e[8];
        float tmax = -1e30f;
        #pragma unroll
        for (int r = 0; r < 4; ++r) {
            const int keya = k0 + 4 * g + r;
            float ea = s0[r] * SCALEC;
            if (keya > q0 + c) ea -= NEGC;
            if (mia[r] == 0)   ea -= NEGC;
            e[r] = ea;
            const int keyb = k0 + 16 + 4 * g + r;
            float eb = s1[r] * SCALEC;
            if (keyb > q0 + c) eb -= NEGC;
            if (mib[r] == 0)   eb -= NEGC;
            e[4 + r] = eb;
            tmax = fmaxf(tmax, fmaxf(ea, eb));
        }
        tmax = fmaxf(tmax, __shfl_xor(tmax, 16));
        tmax = fmaxf(tmax, __shfl_xor(tmax, 32));

        // --- defer-rescale: only rescale when some row's max grew (exact)
        if (__any(tmax > m)) {
            const float mnew = fmaxf(m, tmax);
            const float corr = __expf(m - mnew);
            m = mnew;
            l *= corr;
            float cq[4];
            #pragma unroll
            for (int r = 0; r < 4; ++r) cq[r] = __shfl(corr, 4 * g + r);
            #pragma unroll
            for (int t = 0; t < 4; ++t)
                #pragma unroll
                for (int r = 0; r < 4; ++r) acc[t][r] *= cq[r];
        }

        float p[8], ps = 0.f;
        #pragma unroll
        for (int j = 0; j < 8; ++j) { p[j] = __expf(e[j] - m); ps += p[j]; }
        l += ps;

        short8 pf;
        #pragma unroll
        for (int j = 0; j < 8; ++j) pf[j] = (short)f32_to_bf16_bits(p[j]);

        // --- PV (V fragments already in flight/registers)
        #pragma unroll
        for (int t = 0; t < 4; ++t) {
            const short8 vf = {va[t][0], va[t][1], va[t][2], va[t][3],
                               vb[t][0], vb[t][1], vb[t][2], vb[t][3]};
            acc[t] = __builtin_amdgcn_mfma_f32_16x16x32_bf16(pf, vf, acc[t], 0, 0, 0);
        }
    }

    // reduce l across the 4 g-groups (m already group-uniform per q-row c)
    l = l + __shfl_xor(l, 16);
    l = l + __shfl_xor(l, 32);

    // stage partials
    if (g == 0) { Lm[wave][c] = m; Ll[wave][c] = l; }
    #pragma unroll
    for (int t = 0; t < 4; ++t)
        #pragma unroll
        for (int r = 0; r < 4; ++r)
            Lacc[wave][4 * g + r][t * 16 + c] = acc[t][r];
    __syncthreads();

    // combine: wave w handles d-columns [w*16, w*16+16); each lane 4 rows
    const int col = wave * 16 + c;
    #pragma unroll
    for (int r = 0; r < 4; ++r) {
        const int row = 4 * g + r;
        const float m0v = Lm[0][row], m1v = Lm[1][row];
        const float m2v = Lm[2][row], m3v = Lm[3][row];
        const float M = fmaxf(fmaxf(m0v, m1v), fmaxf(m2v, m3v));
        const float w0 = __expf(m0v - M), w1 = __expf(m1v - M);
        const float w2 = __expf(m2v - M), w3 = __expf(m3v - M);
        const float L = w0 * Ll[0][row] + w1 * Ll[1][row] +
                        w2 * Ll[2][row] + w3 * Ll[3][row];
        const float o = w0 * Lacc[0][row][col] + w1 * Lacc[1][row][col] +
                        w2 * Lacc[2][row][col] + w3 * Lacc[3][row][col];
        Ob[(size_t)(b * Sc + q0 + row) * Dc + h * HDc + col] =
            f32_to_bf16_bits(o / L);
    }
}

// ---------------------------------------------------------------------------
extern "C" void kernel_launch(void* const* d_in, const int* in_sizes, int n_in,
                              void* d_out, int out_size, void* d_ws, size_t ws_size,
                              hipStream_t stream) {
    const float* x  = (const float*)d_in[0];
    const int* mask = (const int*)d_in[1];
    const float* Wq = (const float*)d_in[2];
    const float* bq = (const float*)d_in[3];
    const float* Wk = (const float*)d_in[4];
    const float* bk = (const float*)d_in[5];
    const float* Wv = (const float*)d_in[6];
    const float* bv = (const float*)d_in[7];
    const float* Wo = (const float*)d_in[8];
    const float* bo = (const float*)d_in[9];
    float* out = (float*)d_out;   // reference output dtype is float32

    // workspace layout (ushort elems):
    unsigned short* Xb = (unsigned short*)d_ws;          // 2M   (4 MB)
    unsigned short* Wt = Xb + (size_t)Mtot * 512;        // 4x256K (2 MB)
    unsigned short* Qh = Wt + (size_t)4 * 512 * 512;     // 2M  (Q head-major)
    unsigned short* Kh = Qh + HEADMAT;                   // 2M  (K head-major)
    unsigned short* Vtp = Kh + HEADMAT;                  // 2M  (V head-transposed)
    unsigned short* Ob = Vtp + HEADMAT;                  // 2M
    // total: 18 MB

    // 1) x -> bf16
    convert_x<<<dim3((Mtot * 512) / 1024), dim3(256), 0, stream>>>(
        x, Xb, Mtot * 512);
    // 2) W -> W^T bf16 (all four)
    transpose_w<<<dim3(8, 8, 4), dim3(256), 0, stream>>>(Wq, Wk, Wv, Wo, Wt);
    // 3) QKV projections (+relu): Q,K head-major; V head-transposed
    gemm_mfma<true><<<dim3(8, Mtot / 64, 3), dim3(256), 0, stream>>>(
        Xb, Wt, bq, bk, bv, Qh, nullptr);
    // 4) split-K MFMA flash attention (strided chunks, XCD swizzle) -> Ob
    attn_mfma<<<dim3(2048), dim3(256), 0, stream>>>(
        (const short*)Qh, (const short*)Kh, (const short*)Vtp, mask, Ob);
    // 5) output projection (+relu) -> f32 d_out  (Wo is Wt slot 3)
    gemm_mfma<false><<<dim3(8, Mtot / 64, 1), dim3(256), 0, stream>>>(
        Ob, Wt + (size_t)3 * 512 * 512, bo, bo, bo, nullptr, out);
}

// Round 9
// 108.627 us; speedup vs baseline: 1.9019x; 1.9019x over previous
//
#include <hip/hip_runtime.h>
#include <hip/hip_bf16.h>

// Problem constants (B=2, S=2048, D=512, H=8, hd=64)
constexpr int Bc = 2, Sc = 2048, Dc = 512, Hc = 8, HDc = 64;
constexpr float NEGC = 10000.0f;
constexpr float SCALEC = 0.125f; // 1/sqrt(64)
constexpr int Mtot = Bc * Sc;    // 4096
constexpr size_t HEADMAT = (size_t)Bc * Hc * Sc * HDc;  // 2M elems

typedef __attribute__((ext_vector_type(8))) short          short8;
typedef __attribute__((ext_vector_type(8))) unsigned short ushort8;
typedef __attribute__((ext_vector_type(4))) float          f32x4;

static __device__ __forceinline__ unsigned short f32_to_bf16_bits(float f) {
    unsigned int u = __builtin_bit_cast(unsigned int, f);
    unsigned int r = u + 0x7FFFu + ((u >> 16) & 1u);   // RNE
    return (unsigned short)(r >> 16);
}

// ---------------------------------------------------------------------------
// x f32 -> bf16 (row-major [M][512] unchanged layout)
// ---------------------------------------------------------------------------
__global__ __launch_bounds__(256)
void convert_x(const float* __restrict__ x, unsigned short* __restrict__ Xb, int n)
{
    const int i = (blockIdx.x * 256 + threadIdx.x) * 4;
    if (i >= n) return;
    const float4 v = *(const float4*)(x + i);
    ushort4 o;
    o.x = f32_to_bf16_bits(v.x);
    o.y = f32_to_bf16_bits(v.y);
    o.z = f32_to_bf16_bits(v.z);
    o.w = f32_to_bf16_bits(v.w);
    *(ushort4*)(Xb + i) = o;
}

// ---------------------------------------------------------------------------
// W [512][512] f32 -> W^T [512][512] bf16, z = {Wq,Wk,Wv,Wo}. 64x64 LDS tile.
// ---------------------------------------------------------------------------
__global__ __launch_bounds__(256)
void transpose_w(const float* __restrict__ W0, const float* __restrict__ W1,
                 const float* __restrict__ W2, const float* __restrict__ W3,
                 unsigned short* __restrict__ Wt)
{
    __shared__ float T[64][65];
    const int z = blockIdx.z;
    const float* Wp = (z == 0) ? W0 : (z == 1) ? W1 : (z == 2) ? W2 : W3;
    unsigned short* Op = Wt + (size_t)z * 512 * 512;

    const int kt = blockIdx.y * 64, nt = blockIdx.x * 64;
    const int t = threadIdx.x;
    const int r  = t >> 2, c4 = (t & 3) * 16;

    #pragma unroll
    for (int i = 0; i < 4; ++i) {
        const float4 v = *(const float4*)(Wp + (size_t)(kt + r) * 512 + nt + c4 + 4 * i);
        T[r][c4 + 4*i + 0] = v.x;
        T[r][c4 + 4*i + 1] = v.y;
        T[r][c4 + 4*i + 2] = v.z;
        T[r][c4 + 4*i + 3] = v.w;
    }
    __syncthreads();

    const int n = t >> 2, k4 = (t & 3) * 16;
    #pragma unroll
    for (int i = 0; i < 4; ++i) {
        ushort4 o;
        o.x = f32_to_bf16_bits(T[k4 + 4*i + 0][n]);
        o.y = f32_to_bf16_bits(T[k4 + 4*i + 1][n]);
        o.z = f32_to_bf16_bits(T[k4 + 4*i + 2][n]);
        o.w = f32_to_bf16_bits(T[k4 + 4*i + 3][n]);
        *(ushort4*)(Op + (size_t)(nt + n) * 512 + kt + k4 + 4 * i) = o;
    }
}

// ---------------------------------------------------------------------------
// Tiled bf16 MFMA GEMM (m97-lineage, reg-staged LDS): Y = relu(X @ W + b).
// Tile 128m x 64n, BK=32, 4 waves in 2x2, each wave 64x32 (acc[4][2]).
// A-tile [128][32] (8KB) + B-tile [64][32] (4KB) staged to LDS per K-step;
// stage writes and frag reads are 1KB-contiguous per instruction ->
// conflict-free. 2 barriers per K-step (verified m90-m97 pattern).
// HEADOUT: Q,K,V -> bf16 head-major [z][B][H][S][64]; else f32 [M][512].
// ---------------------------------------------------------------------------
template<bool HEADOUT>
__global__ __launch_bounds__(256)
void gemm_tile(const unsigned short* __restrict__ Xb,
               const unsigned short* __restrict__ Wt,
               const float* __restrict__ b0, const float* __restrict__ b1,
               const float* __restrict__ b2,
               unsigned short* __restrict__ Hout,
               float* __restrict__ Yf)
{
    __shared__ short As[128 * 32];   // [m][k] 8KB
    __shared__ short Bs[64 * 32];    // [n][k] 4KB

    const int lane = threadIdx.x & 63, wave = threadIdx.x >> 6;
    const int c = lane & 15, g = lane >> 4;
    const int wr = wave >> 1, wc = wave & 1;
    const int z = blockIdx.z;
    const unsigned short* Wp = Wt + (size_t)z * 512 * 512;
    const float* bp = (z == 0) ? b0 : (z == 1) ? b1 : b2;
    const int bm = blockIdx.y * 128;
    const int bn = blockIdx.x * 64;

    const int srow = lane >> 2;        // 0..15 within a 16-row chunk
    const int scol = (lane & 3) * 8;   // short offset 0,8,16,24

    f32x4 acc[4][2] = {};

    for (int k0 = 0; k0 < 512; k0 += 32) {
        __syncthreads();   // previous iter's readers done before overwrite
        // stage A (8 chunks of 16 rows; wave does chunks 2w, 2w+1)
        #pragma unroll
        for (int i = 0; i < 2; ++i) {
            const int row = (wave * 2 + i) * 16 + srow;
            const short8 v = *(const short8*)(Xb + (size_t)(bm + row) * 512 + k0 + scol);
            *(short8*)(&As[row * 32 + scol]) = v;
        }
        // stage B (4 chunks; wave does chunk w)
        {
            const int row = wave * 16 + srow;
            const short8 v = *(const short8*)(Wp + (size_t)(bn + row) * 512 + k0 + scol);
            *(short8*)(&Bs[row * 32 + scol]) = v;
        }
        __syncthreads();

        short8 a[4], b[2];
        #pragma unroll
        for (int mi = 0; mi < 4; ++mi)
            a[mi] = *(const short8*)(&As[(wr * 64 + mi * 16 + c) * 32 + g * 8]);
        #pragma unroll
        for (int ni = 0; ni < 2; ++ni)
            b[ni] = *(const short8*)(&Bs[(wc * 32 + ni * 16 + c) * 32 + g * 8]);
        #pragma unroll
        for (int mi = 0; mi < 4; ++mi)
            #pragma unroll
            for (int ni = 0; ni < 2; ++ni)
                acc[mi][ni] = __builtin_amdgcn_mfma_f32_16x16x32_bf16(
                    a[mi], b[ni], acc[mi][ni], 0, 0, 0);
    }

    #pragma unroll
    for (int mi = 0; mi < 4; ++mi) {
        #pragma unroll
        for (int ni = 0; ni < 2; ++ni) {
            const int n = bn + wc * 32 + ni * 16 + c;
            const float bias = bp[n];
            float v[4];
            #pragma unroll
            for (int r = 0; r < 4; ++r)
                v[r] = fmaxf(acc[mi][ni][r] + bias, 0.0f);
            const int mbase = bm + wr * 64 + mi * 16 + 4 * g;
            if constexpr (HEADOUT) {
                const int bb = mbase >> 11, ss = mbase & 2047;
                const int hh = n >> 6, hd = n & 63;
                #pragma unroll
                for (int r = 0; r < 4; ++r)
                    Hout[(size_t)z * HEADMAT +
                         (((size_t)(bb * Hc + hh) * Sc + ss + r) * HDc + hd)] =
                        f32_to_bf16_bits(v[r]);
            } else {
                #pragma unroll
                for (int r = 0; r < 4; ++r)
                    Yf[(size_t)(mbase + r) * 512 + n] = v[r];
            }
        }
    }
}

// ---------------------------------------------------------------------------
// Split-K MFMA flash attention, v5 (= R7 structure + balanced chunks).
// Block = 16 q-rows of one (b,h); 4 waves take BALANCED contiguous chunks of
// ceil(nTiles/4) 32-key tiles (kend ~ q0+16 is uniform, so fixed-512 chunks
// left waves idle; balanced cuts block makespan ~1.7x).
// - XCD swizzle: swz=(bid&7)*256+(bid>>3) -> 2 heads per XCD, K/V L2-resident.
// - V head-major; staged per-tile to wave-PRIVATE LDS via coalesced 16B
//   loads issued early (latency hides under QK^T+softmax). No loop barriers.
// - Defer-rescale: skip corr/rescale when __any(tmax > m) is false (exact).
// - Combine partials in LDS overlay (stride 68: 2-way banks); empty chunks
//   carry weight exactly 0.0f (f32 underflow), matching reference.
// ---------------------------------------------------------------------------
__global__ __launch_bounds__(256)
void attn_mfma(const short* __restrict__ Qh, const short* __restrict__ Kh,
               const short* __restrict__ Vh, const int* __restrict__ mask,
               unsigned short* __restrict__ Ob)
{
    // per-wave 4608B region: loop = V stage [32][72] bf16 (4608B);
    // combine overlay = Lacc[16][68] f32 (4352B) + m[16],l[16] (128B)
    __shared__ __align__(16) char smem[4 * 4608];

    const int lane = threadIdx.x & 63;
    const int wave = threadIdx.x >> 6;
    const int bid = blockIdx.x;
    const int swz = (bid & 7) * 256 + (bid >> 3);   // 2048 % 8 == 0: bijective
    const int qt  = swz & 127;
    const int h   = (swz >> 7) & 7;
    const int b   = swz >> 10;
    const int q0  = qt * 16;
    const int c   = lane & 15;
    const int g   = lane >> 4;

    short* vst      = (short*)(smem + wave * 4608);          // [32][72]
    float* LaccMine = (float*)(smem + wave * 4608);          // [16][68]
    float* LmlMine  = (float*)(smem + wave * 4608 + 4352);   // m[16], l[16]

    const size_t headoff = (size_t)(b * Hc + h) * Sc * HDc;
    const short* Qp = Qh + headoff;
    const short* Kp = Kh + headoff;
    const short* Vp = Vh + headoff;
    const int* mb = mask + b * Sc;

    // first unmasked key index (block-uniform)
    int fb = Sc;
    for (int base = 0; base < Sc; base += 64) {
        unsigned long long bal = __ballot(mb[base + lane] != 0);
        if (bal) { fb = base + (__ffsll((unsigned long long)bal) - 1); break; }
    }
    const int kmax = (fb <= q0) ? (q0 + 16) : Sc;
    const int kend = (kmax + 31) & ~31;

    // balanced contiguous chunks: wave w gets tiles [w*tpw, (w+1)*tpw)
    const int nT   = kend >> 5;
    const int tpw  = (nT + 3) >> 2;
    const int kbeg = wave * tpw * 32;
    const int kfin = min(kend, kbeg + tpw * 32);

    const short8 qf0 = *(const short8*)(Qp + (size_t)(q0 + c) * HDc + g * 8);
    const short8 qf1 = *(const short8*)(Qp + (size_t)(q0 + c) * HDc + 32 + g * 8);

    f32x4 acc[4] = {{0.f,0.f,0.f,0.f},{0.f,0.f,0.f,0.f},
                    {0.f,0.f,0.f,0.f},{0.f,0.f,0.f,0.f}};
    float m = -1e30f, l = 0.0f;

    const int vrow = lane >> 1;            // 0..31
    const int vcol = (lane & 1) * 32;      // 0 or 32

    for (int k0 = kbeg; k0 < kfin; k0 += 32) {
        // --- issue V tile loads early (latency hides under QK^T + softmax)
        const short* vsrc = Vp + (size_t)(k0 + vrow) * HDc + vcol;
        const ushort8 vr0 = *(const ushort8*)(vsrc + 0);
        const ushort8 vr1 = *(const ushort8*)(vsrc + 8);
        const ushort8 vr2 = *(const ushort8*)(vsrc + 16);
        const ushort8 vr3 = *(const ushort8*)(vsrc + 24);

        // --- QK^T
        const short8 kf0a = *(const short8*)(Kp + (size_t)(k0 + c) * HDc + g * 8);
        const short8 kf0b = *(const short8*)(Kp + (size_t)(k0 + c) * HDc + 32 + g * 8);
        const short8 kf1a = *(const short8*)(Kp + (size_t)(k0 + 16 + c) * HDc + g * 8);
        const short8 kf1b = *(const short8*)(Kp + (size_t)(k0 + 16 + c) * HDc + 32 + g * 8);

        f32x4 s0 = {0.f, 0.f, 0.f, 0.f};
        f32x4 s1 = {0.f, 0.f, 0.f, 0.f};
        s0 = __builtin_amdgcn_mfma_f32_16x16x32_bf16(kf0a, qf0, s0, 0, 0, 0);
        s0 = __builtin_amdgcn_mfma_f32_16x16x32_bf16(kf0b, qf1, s0, 0, 0, 0);
        s1 = __builtin_amdgcn_mfma_f32_16x16x32_bf16(kf1a, qf0, s1, 0, 0, 0);
        s1 = __builtin_amdgcn_mfma_f32_16x16x32_bf16(kf1b, qf1, s1, 0, 0, 0);

        const int4 mka = *(const int4*)(mb + k0 + 4 * g);
        const int4 mkb = *(const int4*)(mb + k0 + 16 + 4 * g);
        const int mia[4] = {mka.x, mka.y, mka.z, mka.w};
        const int mib[4] = {mkb.x, mkb.y, mkb.z, mkb.w};

        float e[8];
        float tmax = -1e30f;
        #pragma unroll
        for (int r = 0; r < 4; ++r) {
            const int keya = k0 + 4 * g + r;
            float ea = s0[r] * SCALEC;
            if (keya > q0 + c) ea -= NEGC;
            if (mia[r] == 0)   ea -= NEGC;
            e[r] = ea;
            const int keyb = k0 + 16 + 4 * g + r;
            float eb = s1[r] * SCALEC;
            if (keyb > q0 + c) eb -= NEGC;
            if (mib[r] == 0)   eb -= NEGC;
            e[4 + r] = eb;
            tmax = fmaxf(tmax, fmaxf(ea, eb));
        }
        tmax = fmaxf(tmax, __shfl_xor(tmax, 16));
        tmax = fmaxf(tmax, __shfl_xor(tmax, 32));

        // defer-rescale: only when some row's max grew (bit-exact otherwise)
        if (__any(tmax > m)) {
            const float mnew = fmaxf(m, tmax);
            const float corr = __expf(m - mnew);
            m = mnew;
            l *= corr;
            float cq[4];
            #pragma unroll
            for (int r = 0; r < 4; ++r) cq[r] = __shfl(corr, 4 * g + r);
            #pragma unroll
            for (int t = 0; t < 4; ++t)
                #pragma unroll
                for (int r = 0; r < 4; ++r) acc[t][r] *= cq[r];
        }

        float p[8], ps = 0.f;
        #pragma unroll
        for (int j = 0; j < 8; ++j) { p[j] = __expf(e[j] - m); ps += p[j]; }
        l += ps;

        short8 pf;
        #pragma unroll
        for (int j = 0; j < 8; ++j) pf[j] = (short)f32_to_bf16_bits(p[j]);

        // --- V regs -> private LDS (no barrier)
        short* vdst = vst + vrow * 72 + vcol;
        *(ushort8*)(vdst + 0)  = vr0;
        *(ushort8*)(vdst + 8)  = vr1;
        *(ushort8*)(vdst + 16) = vr2;
        *(ushort8*)(vdst + 24) = vr3;

        // --- PV from LDS
        #pragma unroll
        for (int t = 0; t < 4; ++t) {
            short8 vf;
            #pragma unroll
            for (int j = 0; j < 4; ++j) {
                vf[j]     = vst[(4 * g + j) * 72      + t * 16 + c];
                vf[4 + j] = vst[(16 + 4 * g + j) * 72 + t * 16 + c];
            }
            acc[t] = __builtin_amdgcn_mfma_f32_16x16x32_bf16(pf, vf, acc[t], 0, 0, 0);
        }
    }

    // reduce l across the 4 g-groups (m already group-uniform per q-row c)
    l = l + __shfl_xor(l, 16);
    l = l + __shfl_xor(l, 32);

    // stage partials into OWN region (own V stage is dead now)
    if (g == 0) { LmlMine[c] = m; LmlMine[16 + c] = l; }
    #pragma unroll
    for (int t = 0; t < 4; ++t)
        #pragma unroll
        for (int r = 0; r < 4; ++r)
            LaccMine[(4 * g + r) * 68 + t * 16 + c] = acc[t][r];
    __syncthreads();

    // combine: wave w handles d-columns [w*16, w*16+16); each lane 4 rows
    const int col = wave * 16 + c;
    #pragma unroll
    for (int r = 0; r < 4; ++r) {
        const int row = 4 * g + r;
        float mu[4], lu[4], ou[4];
        #pragma unroll
        for (int u = 0; u < 4; ++u) {
            const float* LaccU = (const float*)(smem + u * 4608);
            const float* LmlU  = (const float*)(smem + u * 4608 + 4352);
            mu[u] = LmlU[row];
            lu[u] = LmlU[16 + row];
            ou[u] = LaccU[row * 68 + col];
        }
        const float M = fmaxf(fmaxf(mu[0], mu[1]), fmaxf(mu[2], mu[3]));
        float L = 0.f, o = 0.f;
        #pragma unroll
        for (int u = 0; u < 4; ++u) {
            const float w = __expf(mu[u] - M);
            L += w * lu[u];
            o += w * ou[u];
        }
        Ob[(size_t)(b * Sc + q0 + row) * Dc + h * HDc + col] =
            f32_to_bf16_bits(o / L);
    }
}

// ---------------------------------------------------------------------------
extern "C" void kernel_launch(void* const* d_in, const int* in_sizes, int n_in,
                              void* d_out, int out_size, void* d_ws, size_t ws_size,
                              hipStream_t stream) {
    const float* x  = (const float*)d_in[0];
    const int* mask = (const int*)d_in[1];
    const float* Wq = (const float*)d_in[2];
    const float* bq = (const float*)d_in[3];
    const float* Wk = (const float*)d_in[4];
    const float* bk = (const float*)d_in[5];
    const float* Wv = (const float*)d_in[6];
    const float* bv = (const float*)d_in[7];
    const float* Wo = (const float*)d_in[8];
    const float* bo = (const float*)d_in[9];
    float* out = (float*)d_out;   // reference output dtype is float32

    // workspace layout (ushort elems):
    unsigned short* Xb = (unsigned short*)d_ws;          // 2M   (4 MB)
    unsigned short* Wt = Xb + (size_t)Mtot * 512;        // 4x256K (2 MB)
    unsigned short* Qh = Wt + (size_t)4 * 512 * 512;     // 2M  (head-major)
    unsigned short* Kh = Qh + HEADMAT;                   // 2M  (head-major)
    unsigned short* Vh = Kh + HEADMAT;                   // 2M  (head-major)
    unsigned short* Ob = Vh + HEADMAT;                   // 2M
    // total: 18 MB

    // 1) x -> bf16
    convert_x<<<dim3((Mtot * 512) / 1024), dim3(256), 0, stream>>>(
        x, Xb, Mtot * 512);
    // 2) W -> W^T bf16 (all four)
    transpose_w<<<dim3(8, 8, 4), dim3(256), 0, stream>>>(Wq, Wk, Wv, Wo, Wt);
    // 3) QKV projections (+relu) -> bf16 head-major, tiled GEMM
    gemm_tile<true><<<dim3(8, Mtot / 128, 3), dim3(256), 0, stream>>>(
        Xb, Wt, bq, bk, bv, Qh, nullptr);
    // 4) split-K MFMA flash attention (balanced chunks, XCD swizzle) -> Ob
    attn_mfma<<<dim3(2048), dim3(256), 0, stream>>>(
        (const short*)Qh, (const short*)Kh, (const short*)Vh, mask, Ob);
    // 5) output projection (+relu) -> f32 d_out  (Wo is Wt slot 3)
    gemm_tile<false><<<dim3(8, Mtot / 128, 1), dim3(256), 0, stream>>>(
        Ob, Wt + (size_t)3 * 512 * 512, bo, bo, bo, nullptr, out);
}